// Round 4
// baseline (396.695 us; speedup 1.0000x reference)
//
#include <hip/hip_runtime.h>

#define NB 8
#define CH 128
#define HH 160
#define WW 160
#define SPILL 100
#define LDS_ROWS 60   // rows [100..159] in LDS: 60*128*4 = 30720 B (+64B halo) -> 5 blocks/CU

// DPP full-wave shifts; bound_ctrl=1 zero-fills out-of-wave = channel zero-padding.
__device__ __forceinline__ float dpp_up1(float x) {   // lane i <- lane i-1, lane 0 <- 0
    return __int_as_float(__builtin_amdgcn_update_dpp(0, __float_as_int(x), 0x138, 0xF, 0xF, true));
}
__device__ __forceinline__ float dpp_dn1(float x) {   // lane i <- lane i+1, lane 63 <- 0
    return __int_as_float(__builtin_amdgcn_update_dpp(0, __float_as_int(x), 0x130, 0xF, 0xF, true));
}

// ---- 2 ch/lane conv (used by k2, unchanged from the 332us version) ----
__device__ __forceinline__ float2 conv9(float2 p, const float* w, float b) {
    float m1x = dpp_up1(p.x), m1y = dpp_up1(p.y);
    float m2x = dpp_up1(m1x), m2y = dpp_up1(m1y);
    float p1x = dpp_dn1(p.x), p1y = dpp_dn1(p.y);
    float p2x = dpp_dn1(p1x), p2y = dpp_dn1(p1y);
    float e0=m2x,e1=m2y,e2=m1x,e3=m1y,e4=p.x,e5=p.y,e6=p1x,e7=p1y,e8=p2x,e9=p2y;
    float ax = fmaf(w[0], e0, b);       ax = fmaf(w[3], e3, ax); ax = fmaf(w[6], e6, ax);
    float bx = w[1]*e1;                 bx = fmaf(w[4], e4, bx); bx = fmaf(w[7], e7, bx);
    float cx = w[2]*e2;                 cx = fmaf(w[5], e5, cx); cx = fmaf(w[8], e8, cx);
    float ay = fmaf(w[0], e1, b);       ay = fmaf(w[3], e4, ay); ay = fmaf(w[6], e7, ay);
    float by = w[1]*e2;                 by = fmaf(w[4], e5, by); by = fmaf(w[7], e8, by);
    float cy = w[2]*e3;                 cy = fmaf(w[5], e6, cy); cy = fmaf(w[8], e9, cy);
    return make_float2((ax + bx) + cx, (ay + by) + cy);
}

// ---- 1 ch/lane conv for the 2-wave k1 (ch = tid, two waves cover 128 ch).
// DPP zero-fills at wave edges; true tensor edges (ch0/ch127) want zeros, the
// interior seam (ch63|ch64) is patched by 4 fma against the LDS halo.
__device__ __forceinline__ float conv9s(float p, const float* w, float b) {
    float m1=dpp_up1(p), m2=dpp_up1(m1), m3=dpp_up1(m2), m4=dpp_up1(m3);
    float q1=dpp_dn1(p), q2=dpp_dn1(q1), q3=dpp_dn1(q2), q4=dpp_dn1(q3);
    float a = fmaf(w[0], m4, b); a = fmaf(w[3], m1, a); a = fmaf(w[6], q2, a);
    float c = w[1]*m3;           c = fmaf(w[4], p,  c); c = fmaf(w[7], q3, c);
    float e = w[2]*m2;           e = fmaf(w[5], q1, e); e = fmaf(w[8], q4, e);
    return (a + c) + e;
}

// K0: NCHW -> NHWC. Tile: 32 c x 128 p. (unchanged from the 332 us version)
__global__ __launch_bounds__(256) void k0_transpose(const float* __restrict__ x,
                                                    float* __restrict__ A) {
    __shared__ float t[32][132];
    int p0 = blockIdx.x * 128;
    int c0 = blockIdx.y * 32;
    int n  = blockIdx.z;
    int tid = threadIdx.x;
    const float* xn = x + (size_t)n * CH * HH * WW;
    float* An = A + (size_t)n * HH * WW * CH;
    #pragma unroll
    for (int j = 0; j < 4; j++) {
        int c = j*8 + tid/32;
        int q4 = (tid%32)*4;
        float4 v = *(const float4*)(xn + (size_t)(c0 + c) * (HH*WW) + p0 + q4);
        *(float4*)&t[c][q4] = v;
    }
    __syncthreads();
    #pragma unroll
    for (int j = 0; j < 8; j++) {
        int p  = j*16 + tid/16;
        int cq = (tid%16)*2;
        float2 v = make_float2(t[cq][p], t[cq+1][p]);
        *(float2*)(An + (size_t)(p0 + p) * CH + c0 + cq) = v;
    }
}

// K1: fused down+up scan over H. NEW: 2 waves per column (1 channel/lane),
// 2560 waves total = 10 waves/CU (was 5) — tests the concurrency-cap theory.
// Seam (ch63|ch64) handled via 8-float LDS halo + 1 barrier/step; per-lane
// seam weights wsD/wsU precomputed (zero on interior lanes).
__global__ __launch_bounds__(128) void k1_vert(float* __restrict__ A,
        const float* __restrict__ wdp, const float* __restrict__ bdp,
        const float* __restrict__ wup, const float* __restrict__ bup) {
    __shared__ float lds[LDS_ROWS][CH];   // relu(d) rows 100..159, [r][ch]
    __shared__ float halo[2][8];          // [parity][0..3]=ch60..63, [4..7]=ch64..67
    int tid  = threadIdx.x;
    int lane = tid & 63;
    int wid  = tid >> 6;          // 0: ch 0-63, 1: ch 64-127
    int ch   = tid;
    int w = blockIdx.x, n = blockIdx.y;
    float wd[9], wu[9];
    #pragma unroll
    for (int j = 0; j < 9; j++) { wd[j] = wdp[j]; wu[j] = wup[j]; }
    float bd = bdp[0], bu = bup[0];

    // per-lane seam-correction weights (global-indexed loads: no dynamic
    // register-array indexing -> no scratch). Zero on non-seam lanes.
    float wsD[4], wsU[4];
    #pragma unroll
    for (int j = 0; j < 4; j++) {
        float a = 0.f, b2 = 0.f;
        if (wid == 0) { int t = lane - 60; if (t >= 0 && j <= t) { a = wdp[8-t+j]; b2 = wup[8-t+j]; } }
        else          { if (lane < 4 && j >= lane)              { a = wdp[j-lane]; b2 = wup[j-lane]; } }
        wsD[j] = a; wsU[j] = b2;
    }
    bool pub  = (wid == 0) ? (lane >= 60) : (lane < 4);
    int hslot = (wid == 0) ? (lane - 60) : (4 + lane);
    int hoff  = wid ? 0 : 4;      // wave0 reads ch64..67, wave1 reads ch60..63

    float* col = A + ((size_t)n * HH * WW + w) * CH + ch;
    const size_t RS = (size_t)WW * CH;

    // ---- down: d[h] = relu(conv(d[h-1]))+x[h]; rows<SPILL spill relu in-place, rest LDS ----
    float d;
    float qf[16];
    #pragma unroll
    for (int i = 0; i < 16; i++) qf[i] = col[(size_t)i * RS];
    int par = 0;
    for (int hb = 0; hb < HH; hb += 16) {
        #pragma unroll
        for (int k = 0; k < 16; k++) {
            int h = hb + k;
            float xr = qf[k];
            if (h + 16 < HH) qf[k] = col[(size_t)(h+16) * RS];
            if (h == 0) d = xr;
            else {
                float4 hv = *(const float4*)&halo[par][hoff];
                float cv = conv9s(d, wd, bd);
                cv = fmaf(wsD[0], hv.x, cv); cv = fmaf(wsD[1], hv.y, cv);
                cv = fmaf(wsD[2], hv.z, cv); cv = fmaf(wsD[3], hv.w, cv);
                d = fmaxf(cv, 0.f) + xr;
                par ^= 1;
            }
            if (pub) halo[par][hslot] = d;
            __syncthreads();
            float rd = fmaxf(d, 0.f);
            if (h < SPILL) col[(size_t)h * RS] = rd;
            else           lds[h-SPILL][ch] = rd;
        }
    }

    // ---- up: u[s] = relu(conv(u[s-1]))+relu(d[159-s]); 16-deep mixed LDS/global ring ----
    float u;
    float tf[16];
    #pragma unroll
    for (int k = 0; k < 16; k++) tf[k] = lds[59 - k][ch];   // h = 159..144
    for (int sb = 0; sb < HH; sb += 16) {
        #pragma unroll
        for (int k = 0; k < 16; k++) {
            int s = sb + k;
            int h = HH - 1 - s;
            float t2 = tf[k];
            int h2 = h - 16;
            if (h2 >= SPILL)    tf[k] = lds[h2-SPILL][ch];
            else if (h2 >= 0)   tf[k] = col[(size_t)h2 * RS];
            if (s == 0) u = t2;
            else {
                float4 hv = *(const float4*)&halo[par][hoff];
                float cv = conv9s(u, wu, bu);
                cv = fmaf(wsU[0], hv.x, cv); cv = fmaf(wsU[1], hv.y, cv);
                cv = fmaf(wsU[2], hv.z, cv); cv = fmaf(wsU[3], hv.w, cv);
                u = fmaxf(cv, 0.f) + t2;
                par ^= 1;
            }
            if (pub) halo[par][hslot] = u;
            __syncthreads();
            col[(size_t)h * RS] = u;
        }
    }
}

// K2: fused left+right scan over W + fused flip-transpose output (exact 332us version).
__global__ __launch_bounds__(64) void k2_horz(float* __restrict__ A,
        const float* __restrict__ wlp, const float* __restrict__ blp,
        const float* __restrict__ wrp, const float* __restrict__ brp,
        float* __restrict__ out) {
    __shared__ float lds[LDS_ROWS][CH];
    int lane = threadIdx.x;
    int hp = blockIdx.x, n = blockIdx.y;
    float wl[9], wr[9];
    #pragma unroll
    for (int j = 0; j < 9; j++) { wl[j] = wlp[j]; wr[j] = wrp[j]; }
    float bl = blp[0], br = brp[0];
    float* row0 = A + ((size_t)n * HH + hp) * WW * CH + 2*lane;
    const size_t PS = CH;

    // ---- left scan: spill relu(l); rows >=SPILL to swizzled LDS ----
    float2 l;
    float2 qf[16];
    #pragma unroll
    for (int i = 0; i < 16; i++) qf[i] = *(const float2*)(row0 + (size_t)i * PS);
    for (int ab = 0; ab < WW; ab += 16) {
        #pragma unroll
        for (int k = 0; k < 16; k++) {
            int a = ab + k;
            float2 xr = qf[k];
            if (a + 16 < WW) qf[k] = *(const float2*)(row0 + (size_t)(a+16) * PS);
            xr.x = fmaxf(xr.x, 0.f); xr.y = fmaxf(xr.y, 0.f);
            if (a == 0) l = xr;
            else {
                float2 cv = conv9(l, wl, bl);
                l.x = fmaxf(cv.x, 0.f) + xr.x;
                l.y = fmaxf(cv.y, 0.f) + xr.y;
            }
            float rx = fmaxf(l.x, 0.f), ry = fmaxf(l.y, 0.f);
            if (a < SPILL) *(float2*)(row0 + (size_t)a * PS) = make_float2(rx, ry);
            else {
                int r = a - SPILL;
                int sw = r & 31;
                lds[r][lane ^ sw] = rx;
                lds[r][64 + (lane ^ sw)] = ry;
            }
        }
    }

    // ---- right scan with fused flipped-transposed output ----
    float2 u;
    float2 tf[16];
    #pragma unroll
    for (int k = 0; k < 16; k++) {
        int a = WW - 1 - k;              // 159..144, all >= SPILL
        int r = a - SPILL;
        int sw = r & 31;
        tf[k] = make_float2(lds[r][lane ^ sw], lds[r][64 + (lane ^ sw)]);
    }
    int ho  = HH - 1 - hp;
    int l31 = lane & 31;
    int hi  = lane >> 5;
    float* ob = out + ((size_t)(n * CH + hi) * HH + ho) * WW + l31;
    int jf = (179 - l31) % 60;    // tile row holding w' = l31 of the current block
    int js = 59;                  // tile row for current step s (decrements, wraps 0->59)

    for (int sb = 0; sb < WW; sb += 32) {
        #pragma unroll
        for (int kk = 0; kk < 32; kk++) {
            int s = sb + kk;
            int a = WW - 1 - s;
            float2 t6 = tf[kk & 15];
            int a2 = a - 16;
            if (a2 >= SPILL) {
                int r = a2 - SPILL;
                int sw = r & 31;
                tf[kk & 15] = make_float2(lds[r][lane ^ sw], lds[r][64 + (lane ^ sw)]);
            } else if (a2 >= 0) {
                tf[kk & 15] = *(const float2*)(row0 + (size_t)a2 * PS);
            }
            if (s == 0) u = t6;
            else {
                float2 cv = conv9(u, wr, br);
                u.x = fmaxf(cv.x, 0.f) + t6.x;
                u.y = fmaxf(cv.y, 0.f) + t6.y;
            }
            {
                int sw = js & 31;
                lds[js][lane ^ sw]        = fmaxf(u.x, 0.f);
                lds[js][64 + (lane ^ sw)] = fmaxf(u.y, 0.f);
            }
            js = js ? js - 1 : 59;
        }
        {
            int jx = jf & 31;
            int pl = jf * 128 + (hi << 6);
            const float* lp = &lds[0][0];
            #pragma unroll
            for (int i = 0; i < 64; i++) {
                float v = lp[pl + (i ^ jx)];
                ob[(size_t)(2*i) * (HH*WW) + sb] = v;
            }
            jf -= 32; if (jf < 0) jf += 60;
        }
    }
}

extern "C" void kernel_launch(void* const* d_in, const int* in_sizes, int n_in,
                              void* d_out, int out_size, void* d_ws, size_t ws_size,
                              hipStream_t stream) {
    (void)in_sizes; (void)n_in; (void)out_size; (void)ws_size;
    const float* x  = (const float*)d_in[0];
    const float* wd = (const float*)d_in[1];
    const float* bd = (const float*)d_in[2];
    const float* wu = (const float*)d_in[3];
    const float* bu = (const float*)d_in[4];
    const float* wl = (const float*)d_in[5];
    const float* bl = (const float*)d_in[6];
    const float* wr = (const float*)d_in[7];
    const float* br = (const float*)d_in[8];
    float* out = (float*)d_out;
    float* A   = (float*)d_ws;   // needs N*H*W*C*4 = 104,857,600 bytes

    dim3 g0(HH*WW/128, CH/32, NB), b0(256);
    k0_transpose<<<g0, b0, 0, stream>>>(x, A);

    dim3 g1(WW, NB), b1(128);
    k1_vert<<<g1, b1, 0, stream>>>(A, wd, bd, wu, bu);

    dim3 g2(HH, NB), b2(64);
    k2_horz<<<g2, b2, 0, stream>>>(A, wl, bl, wr, br, out);
}